// Round 4
// baseline (386.044 us; speedup 1.0000x reference)
//
#include <hip/hip_runtime.h>

#define S    4096
#define CH   256
#define NB   8

#define BM   128
#define BN   128
#define CK   16
#define KSPLIT 8

#define NEG_INF (-3.402823466e38f)

// ---------------------------------------------------------------------------
// out[:, 0:512] = input  (runs AFTER argmax_gemm — that slab is GEMM scratch)
__global__ void copy_fl(const float* __restrict__ x, float* __restrict__ out) {
    int i = blockIdx.x * 256 + threadIdx.x;          // float4 index
    const int per_b = 512 * S / 4;
    int b = i / per_b;
    int r = i - b * per_b;
    const float4* src = (const float4*)x;
    float4* dst = (float4*)out;
    dst[(size_t)b * (768 * S / 4) + r] = src[(size_t)b * per_b + r];
}

// ---------------------------------------------------------------------------
// order-preserving compaction: qlist = {s : flag[s]==1}, klist = {s : flag[s]==0}
__global__ void compact(const int* __restrict__ flag, int* __restrict__ cnts,
                        int* __restrict__ qlist, int* __restrict__ klist) {
    __shared__ int sq[256], sk[256];
    int t = threadIdx.x;
    int base = t * 16;
    int f[16];
    int nq = 0, nk = 0;
    #pragma unroll
    for (int i = 0; i < 16; ++i) {
        f[i] = flag[base + i];
        nq += (f[i] == 1);
        nk += (f[i] == 0);
    }
    sq[t] = nq; sk[t] = nk;
    __syncthreads();
    for (int off = 1; off < 256; off <<= 1) {
        int vq = sq[t], vk = sk[t];
        int aq = (t >= off) ? sq[t - off] : 0;
        int ak = (t >= off) ? sk[t - off] : 0;
        __syncthreads();
        sq[t] = vq + aq; sk[t] = vk + ak;
        __syncthreads();
    }
    int pq = sq[t] - nq;
    int pk = sk[t] - nk;
    #pragma unroll
    for (int i = 0; i < 16; ++i) {
        if (f[i] == 1)      qlist[pq++] = base + i;
        else                klist[pk++] = base + i;
    }
    if (t == 255) { cnts[0] = sq[255]; cnts[1] = sk[255]; }
}

// ---------------------------------------------------------------------------
// invn[b][k] = 1 / max(||l[b,k,:]||, 1e-12)   (float4 over k)
__global__ void invnorm_k(const float* __restrict__ x, float* __restrict__ invn) {
    int k4 = blockIdx.x * 256 + threadIdx.x;    // float4 index over k
    int b  = blockIdx.y;
    const float4* base = (const float4*)(x + ((size_t)b * 512 + 256) * S) + k4;
    float4 acc = { 0.f, 0.f, 0.f, 0.f };
    #pragma unroll 8
    for (int c = 0; c < CH; ++c) {
        float4 v = base[(size_t)c * (S / 4)];
        acc.x += v.x * v.x; acc.y += v.y * v.y;
        acc.z += v.z * v.z; acc.w += v.w * v.w;
    }
    float4 r;
    r.x = 1.0f / fmaxf(sqrtf(acc.x), 1e-12f);
    r.y = 1.0f / fmaxf(sqrtf(acc.y), 1e-12f);
    r.z = 1.0f / fmaxf(sqrtf(acc.z), 1e-12f);
    r.w = 1.0f / fmaxf(sqrtf(acc.w), 1e-12f);
    ((float4*)(invn + ((size_t)b << 12)))[k4] = r;
}

// ---------------------------------------------------------------------------
// pack normalized active-k columns of latter into dense [c][j], j = compact k,
// in the out[:,512:768] slab (scratch until scatter_k overwrites it).
__global__ void pack_ln(const float* __restrict__ x, const int* __restrict__ cnts,
                        const int* __restrict__ klist, const float* __restrict__ invn,
                        float* __restrict__ out) {
    int j = blockIdx.x * 256 + threadIdx.x;
    int b = blockIdx.z;
    int Ak = cnts[1];
    int kk = -1; float w = 0.f;
    if (j < Ak) { kk = klist[j]; w = invn[((size_t)b << 12) + kk]; }
    const float* Lm = x + ((size_t)b * 512 + 256) * S;
    float* dst = out + ((size_t)b * 768 + 512) * S;
    #pragma unroll
    for (int c8 = 0; c8 < 8; ++c8) {
        int c = blockIdx.y * 8 + c8;
        dst[(size_t)c * S + j] = (kk >= 0) ? Lm[(size_t)c * S + kk] * w : 0.f;
    }
}

// ---------------------------------------------------------------------------
// pack active-q columns of former into dense [c][i], i = compact q,
// in the out[:,0:256] slab (scratch until copy_fl overwrites it).
__global__ void pack_f(const float* __restrict__ x, const int* __restrict__ cnts,
                       const int* __restrict__ qlist, float* __restrict__ out) {
    int i = blockIdx.x * 256 + threadIdx.x;
    int b = blockIdx.z;
    int Aq = cnts[0];
    int qq = (i < Aq) ? qlist[i] : -1;
    const float* Fm = x + (size_t)b * 512 * S;
    float* dst = out + (size_t)b * 768 * S;
    #pragma unroll
    for (int c8 = 0; c8 < 8; ++c8) {
        int c = blockIdx.y * 8 + c8;
        dst[(size_t)c * S + i] = (qq >= 0) ? Fm[(size_t)c * S + qq] : 0.f;
    }
}

// ---------------------------------------------------------------------------
// dense argmax GEMM, both operands packed: per (b, 128-q tile, k-split) block,
// BM=128 x BN=128, CK=16, 8q x 8k per-thread register tile.
__launch_bounds__(256)
__global__ void argmax_gemm(const float* __restrict__ packed,  // == out
                            const int*  __restrict__ cnts,
                            const int*  __restrict__ klist,
                            float* __restrict__ pmax,
                            int*   __restrict__ pidx) {
    __shared__ float Fs[CK][BM];     // 8 KB
    __shared__ float Ls[CK][BN];     // 8 KB

    const int Aq    = cnts[0];
    const int Ak    = cnts[1];
    const int b     = blockIdx.y;
    const int split = blockIdx.x & (KSPLIT - 1);
    const int q0    = (blockIdx.x >> 3) * BM;
    if (q0 >= Aq) return;

    const int tid = threadIdx.x;
    const int tx  = tid & 15;       // k-cols: tx*4..+3 and 64+tx*4..+3
    const int ty  = tid >> 4;       // q-rows: ty*4..+3 and 64+ty*4..+3

    const float* Fp  = packed + (size_t)b * 768 * S;            // [c][i]
    const float* Lnb = packed + ((size_t)b * 768 + 512) * S;    // [c][j]

    const int nkt = (Ak + BN - 1) / BN;
    const int kt0 = (nkt * split) / KSPLIT;
    const int kt1 = (nkt * (split + 1)) / KSPLIT;

    float rm[8]; int ri[8];
    #pragma unroll
    for (int i = 0; i < 8; ++i) { rm[i] = NEG_INF; ri[i] = 0; }

    for (int kt = kt0; kt < kt1; ++kt) {
        const int kbase = kt * BN;

        float acc[8][8];
        #pragma unroll
        for (int a = 0; a < 8; ++a)
            #pragma unroll
            for (int c = 0; c < 8; ++c) acc[a][c] = 0.f;

        for (int c0 = 0; c0 < CH; c0 += CK) {
            __syncthreads();        // previous chunk's compute done with Fs/Ls
            // stage Fs and Ls: 512 float4 each, 2 per thread, fully coalesced
            #pragma unroll
            for (int p = 0; p < 2; ++p) {
                int v  = p * 256 + tid;
                int cc = v >> 5;
                int x4 = (v & 31) << 2;
                *(float4*)&Fs[cc][x4] =
                    *(const float4*)&Fp[(size_t)(c0 + cc) * S + q0 + x4];
                *(float4*)&Ls[cc][x4] =
                    *(const float4*)&Lnb[(size_t)(c0 + cc) * S + kbase + x4];
            }
            __syncthreads();

            #pragma unroll
            for (int cc = 0; cc < CK; ++cc) {
                const float4 a0 = *(const float4*)&Fs[cc][ty * 4];
                const float4 a1 = *(const float4*)&Fs[cc][64 + ty * 4];
                const float4 b0 = *(const float4*)&Ls[cc][tx * 4];
                const float4 b1 = *(const float4*)&Ls[cc][64 + tx * 4];
                float av[8] = { a0.x, a0.y, a0.z, a0.w, a1.x, a1.y, a1.z, a1.w };
                float bv[8] = { b0.x, b0.y, b0.z, b0.w, b1.x, b1.y, b1.z, b1.w };
                #pragma unroll
                for (int qq = 0; qq < 8; ++qq)
                    #pragma unroll
                    for (int jj = 0; jj < 8; ++jj)
                        acc[qq][jj] += av[qq] * bv[jj];
            }
        }

        // fold k-tile into running (max, idx); ascending-k within thread
        #pragma unroll
        for (int jj = 0; jj < 8; ++jj) {
            int col = (jj < 4) ? (tx * 4 + jj) : (64 + tx * 4 + (jj - 4));
            int kp  = kbase + col;
            if (kp < Ak) {
                int kk = klist[kp];
                #pragma unroll
                for (int qq = 0; qq < 8; ++qq) {
                    float sv = acc[qq][jj];
                    if (sv > rm[qq]) { rm[qq] = sv; ri[qq] = kk; }
                    else if (sv == rm[qq] && kk < ri[qq]) { ri[qq] = kk; }
                }
            }
        }
    }

    // reduce across the 16 lanes sharing each q-row group
    #pragma unroll
    for (int qq = 0; qq < 8; ++qq) {
        float m = rm[qq]; int id = ri[qq];
        #pragma unroll
        for (int off = 8; off; off >>= 1) {
            float om = __shfl_xor(m, off, 64);
            int   oi = __shfl_xor(id, off, 64);
            if (om > m || (om == m && oi < id)) { m = om; id = oi; }
        }
        if (tx == 0) {
            int row = (qq < 4) ? (ty * 4 + qq) : (64 + ty * 4 + (qq - 4));
            int qp  = q0 + row;
            if (qp < Aq) {
                size_t o = ((size_t)((b << 12) + qp)) * KSPLIT + split;
                pmax[o] = m;
                pidx[o] = id;
            }
        }
    }
}

// ---------------------------------------------------------------------------
// combine k-split partials -> idxb[b][q]  (strict > keeps lowest split)
__global__ void combine(const int* __restrict__ cnts, const int* __restrict__ qlist,
                        const float* __restrict__ pmax, const int* __restrict__ pidx,
                        int* __restrict__ idxb) {
    int qp = blockIdx.x * 256 + threadIdx.x;
    int b  = blockIdx.y;
    if (qp >= cnts[0]) return;
    size_t base = (size_t)((b << 12) + qp) * KSPLIT;
    float m = pmax[base]; int id = pidx[base];
    #pragma unroll
    for (int s = 1; s < KSPLIT; ++s) {
        float om = pmax[base + s]; int oi = pidx[base + s];
        if (om > m) { m = om; id = oi; }
    }
    idxb[((size_t)b << 12) + qlist[qp]] = id;
}

// ---------------------------------------------------------------------------
// out[b][512+c][q] = flag[q]==1 ? latter[b][c][idx[b][q]] : 0
__global__ void scatter_k(const float* __restrict__ x, const int* __restrict__ flag,
                          const int* __restrict__ idxb, float* __restrict__ out) {
    int e = blockIdx.x * 256 + threadIdx.x;
    int q = e & (S - 1);
    int c = (e >> 12) & 255;
    int b = e >> 20;
    float v = 0.f;
    if (flag[q] == 1) {
        int id = idxb[((size_t)b << 12) + q];
        v = x[((size_t)b * 512 + 256 + c) * S + id];
    }
    out[((size_t)b * 768 + 512 + c) * S + q] = v;
}

// ---------------------------------------------------------------------------
extern "C" void kernel_launch(void* const* d_in, const int* in_sizes, int n_in,
                              void* d_out, int out_size, void* d_ws, size_t ws_size,
                              hipStream_t stream) {
    const float* x    = (const float*)d_in[0];
    const int*   flag = (const int*)d_in[2];
    float*       out  = (float*)d_out;

    char* ws = (char*)d_ws;
    int*   cnts  = (int*)(ws);                 // 2 ints
    int*   qlist = (int*)(ws + 1024);          // 16 KB
    int*   klist = (int*)(ws + 17408);         // 16 KB
    float* invn  = (float*)(ws + 33792);       // 128 KB
    int*   idxb  = (int*)(ws + 164864);        // 128 KB
    float* pmax  = (float*)(ws + 295936);      // 1 MB  (8*4096*8)
    int*   pidx  = (int*)(ws + 1344512);       // 1 MB

    hipLaunchKernelGGL(compact,     dim3(1),                        dim3(256), 0, stream, flag, cnts, qlist, klist);
    hipLaunchKernelGGL(invnorm_k,   dim3(S / 4 / 256, NB),          dim3(256), 0, stream, x, invn);
    hipLaunchKernelGGL(pack_ln,     dim3(S / 256, CH / 8, NB),      dim3(256), 0, stream, x, cnts, klist, invn, out);
    hipLaunchKernelGGL(pack_f,      dim3(S / 256, CH / 8, NB),      dim3(256), 0, stream, x, cnts, qlist, out);
    hipLaunchKernelGGL(argmax_gemm, dim3((S / BM) * KSPLIT, NB),    dim3(256), 0, stream,
                       out, cnts, klist, pmax, pidx);
    hipLaunchKernelGGL(combine,     dim3(S / 256, NB),              dim3(256), 0, stream, cnts, qlist, pmax, pidx, idxb);
    hipLaunchKernelGGL(copy_fl,     dim3((NB * 512 * S / 4) / 256), dim3(256), 0, stream, x, out);
    hipLaunchKernelGGL(scatter_k,   dim3((NB * CH * S) / 256),      dim3(256), 0, stream, x, flag, idxb, out);
}